// Round 7
// baseline (145.653 us; speedup 1.0000x reference)
//
#include <hip/hip_runtime.h>
#include <cstdint>
#include <cstddef>

#define BB 4
#define NN 32768
#define PRE 4096
#define POST 512
#define NW 64        // u64 words per full mask row = PRE/64
#define PSEL 1024    // prefix selection size (hot path)
#define PREF_CH 16   // PSEL/64 chunks

typedef unsigned long long u64;
typedef unsigned int u32;

// LDS bank-conflict swizzle for the fallback's u64 sort buffer
#define SW(i) ((i) ^ (((i) >> 4) & 15))

__device__ __forceinline__ u32 enc_f32(float f) {
  u32 u = __float_as_uint(f);
  u32 m = (u32)((int)u >> 31) | 0x80000000u;  // neg -> 0xFFFFFFFF, pos -> 0x80000000
  return u ^ m;                                // ascending u <=> ascending f
}

// ---------------- kernel 1: scores = max over 3 classes, labels = argmax ----
__global__ void score_kernel(const float* __restrict__ cls,
                             float* __restrict__ scores, int* __restrict__ labels) {
  int g = blockIdx.x * blockDim.x + threadIdx.x;
  if (g >= BB * NN) return;
  const float* p = cls + (size_t)g * 3;
  float c0 = p[0], c1 = p[1], c2 = p[2];
  float m = c0; int l = 0;
  if (c1 > m) { m = c1; l = 1; }
  if (c2 > m) { m = c2; l = 2; }
  scores[g] = m;
  labels[g] = l;
}

// ======== kernel 2 (hot): top-PSEL select, atomic-free 4-bit radix ==========
// Histogram: per-lane register-packed counts (16 bins x 8-bit fields in 2 u64),
// shfl_xor reduce (widen to 16-bit after 2 steps), 16x16 LDS exchange, single-
// wave suffix scan. No LDS atomics (score clustering made them serialize), 2
// barriers/pass. Compaction + hybrid 1-elem/thread bitonic sort as in round 6.
__global__ __launch_bounds__(1024) void select_fast_kernel(
    const float* __restrict__ scores, const float* __restrict__ boxes,
    int* __restrict__ top_idx, float* __restrict__ top_score,
    float* __restrict__ bx1, float* __restrict__ bx2,
    float* __restrict__ by1, float* __restrict__ by2, float* __restrict__ bar) {
  int b = blockIdx.x;
  int tid = threadIdx.x;
  int lane = tid & 63, wv = tid >> 6;
  const float* sc = scores + (size_t)b * NN;

  __shared__ u32 whist[16][16];   // [wave][bin]
  __shared__ u32 scanbuf[1024];
  __shared__ u64 sortbuf[PSEL];
  __shared__ u32 sh_prefix;
  __shared__ int sh_rem;

  // --- load my 32 contiguous scores ONCE into registers ---
  const int e0 = tid * 32;
  u32 encs[32];
  {
    const float4* sc4 = (const float4*)(sc + e0);
#pragma unroll
    for (int k = 0; k < 8; ++k) {
      float4 v = sc4[k];
      encs[k * 4 + 0] = enc_f32(v.x);
      encs[k * 4 + 1] = enc_f32(v.y);
      encs[k * 4 + 2] = enc_f32(v.z);
      encs[k * 4 + 3] = enc_f32(v.w);
    }
  }

  // --- 8-pass 4-bit radix select of the PSEL-th largest encoded score ---
  u32 prefix = 0, known = 0;
  int remaining = PSEL;
  for (int shift = 28; shift >= 0; shift -= 4) {
    // per-lane packed histogram: bins 0-7 in lo (8-bit fields), 8-15 in hi
    u64 lo = 0, hi = 0;
#pragma unroll
    for (int k = 0; k < 32; ++k) {
      u32 u = encs[k];
      bool act = ((u & known) == prefix);
      int d = (int)((u >> shift) & 15u);
      u64 inc = act ? (1ull << ((d & 7) * 8)) : 0ull;
      if (d < 8) lo += inc; else hi += inc;
    }
    // 2-step reduce in 8-bit fields (max 4*32=128 < 256)
    lo += __shfl_xor(lo, 1, 64); hi += __shfl_xor(hi, 1, 64);
    lo += __shfl_xor(lo, 2, 64); hi += __shfl_xor(hi, 2, 64);
    // widen to 16-bit fields, finish 64-lane reduce (max 2048 < 65536)
    const u64 M8 = 0x00FF00FF00FF00FFull;
    u64 a0 = lo & M8, a1 = (lo >> 8) & M8;   // bins 0,2,4,6 / 1,3,5,7
    u64 b0 = hi & M8, b1 = (hi >> 8) & M8;   // bins 8,10,12,14 / 9,11,13,15
#pragma unroll
    for (int off = 4; off < 64; off <<= 1) {
      a0 += __shfl_xor(a0, off, 64); a1 += __shfl_xor(a1, off, 64);
      b0 += __shfl_xor(b0, off, 64); b1 += __shfl_xor(b1, off, 64);
    }
    // lane b (0..15) extracts this wave's count for bin b
    if (lane < 16) {
      int sub = lane & 7;
      u64 src = (lane < 8) ? ((sub & 1) ? a1 : a0) : ((sub & 1) ? b1 : b0);
      whist[wv][lane] = (u32)((src >> ((sub >> 1) * 16)) & 0xFFFFull);
    }
    __syncthreads();
    if (wv == 0) {
      int bin = lane & 15, grp = lane >> 4;  // 4 lanes/bin, each sums 4 waves
      u32 s = whist[grp * 4 + 0][bin] + whist[grp * 4 + 1][bin] +
              whist[grp * 4 + 2][bin] + whist[grp * 4 + 3][bin];
      s += __shfl_xor(s, 16, 64);
      s += __shfl_xor(s, 32, 64);  // lanes 0-15 now hold total[bin]
      u32 v = s;
#pragma unroll
      for (int off = 1; off < 16; off <<= 1) {
        u32 t = __shfl_down(v, off, 64);
        if (lane + off < 16) v += t;   // inclusive suffix over 16 bins
      }
      u32 vn = __shfl_down(v, 1, 64);  // suffix(bin+1)
      if (lane == 15) vn = 0;
      if (lane < 16 && v >= (u32)remaining && vn < (u32)remaining) {
        sh_prefix = prefix | ((u32)lane << shift);
        sh_rem = remaining - (int)vn;
      }
    }
    __syncthreads();
    prefix = sh_prefix;
    remaining = sh_rem;
    known |= (0xFu << shift);
  }
  const u32 pivot = prefix;

  // --- compaction via positional packed scan (stable for ==pivot) ---
  int gtc = 0, eqc = 0;
#pragma unroll
  for (int k = 0; k < 32; ++k) {
    gtc += (encs[k] > pivot);
    eqc += (encs[k] == pivot);
  }
  scanbuf[tid] = ((u32)gtc << 16) | (u32)eqc;
  __syncthreads();
  for (int off = 1; off < 1024; off <<= 1) {
    u32 v = scanbuf[tid];
    u32 add = (tid >= off) ? scanbuf[tid - off] : 0u;
    __syncthreads();
    scanbuf[tid] = v + add;
    __syncthreads();
  }
  u32 incl = scanbuf[tid];
  u32 totpk = scanbuf[1023];
  const int cnt_gt = (int)(totpk >> 16);         // == PSEL - remaining
  int gt_base = (int)(incl >> 16) - gtc;
  int eq_base = (int)(incl & 0xFFFFu) - eqc;
  int gs = 0, es = 0;
#pragma unroll
  for (int k = 0; k < 32; ++k) {
    u32 u = encs[k];
    int e = e0 + k;
    u64 key = ((u64)u << 32) | (u32)(~(u32)e);
    if (u > pivot) {
      sortbuf[gt_base + (gs++)] = key;
    } else if (u == pivot) {
      int g = eq_base + (es++);
      if (g < remaining) sortbuf[cnt_gt + g] = key;
    }
  }
  __syncthreads();

  // --- hybrid bitonic sort, 1 elem/thread: shfl j<64, LDS j>=64 ---
  u64 key = sortbuf[tid];
#pragma unroll
  for (int k2 = 2; k2 <= 64; k2 <<= 1) {
    for (int j = k2 >> 1; j > 0; j >>= 1) {
      u64 o = __shfl_xor(key, j, 64);
      bool take_max = (((tid & k2) == 0) == ((tid & j) == 0));
      key = ((key > o) == take_max) ? key : o;
    }
  }
  for (int k2 = 128; k2 <= PSEL; k2 <<= 1) {
    for (int j = k2 >> 1; j >= 64; j >>= 1) {
      __syncthreads();
      sortbuf[tid] = key;
      __syncthreads();
      u64 o = sortbuf[tid ^ j];
      bool take_max = (((tid & k2) == 0) == ((tid & j) == 0));
      key = ((key > o) == take_max) ? key : o;
    }
    for (int j = 32; j > 0; j >>= 1) {
      u64 o = __shfl_xor(key, j, 64);
      bool take_max = (((tid & k2) == 0) == ((tid & j) == 0));
      key = ((key > o) == take_max) ? key : o;
    }
  }

  // --- epilogue: one sorted element per thread ---
  {
#pragma clang fp contract(off)
    int e = (int)(~(u32)(key & 0xFFFFFFFFull));
    top_idx[b * PRE + tid] = e;
    top_score[b * PRE + tid] = sc[e];
    const float* bx = boxes + ((size_t)b * NN + e) * 7;
    float x = bx[0], y = bx[1], dx = bx[3], dy = bx[4];
    float hx = dx * 0.5f, hy = dy * 0.5f;
    bx1[b * PRE + tid] = x - hx;
    bx2[b * PRE + tid] = x + hx;
    by1[b * PRE + tid] = y - hy;
    by2[b * PRE + tid] = y + hy;
    bar[b * PRE + tid] = dx * dy;
  }
}

// ======== kernel 2' (cold fallback): round-4 top-PRE select (gated) =========
template<int SELN, bool GATED>
__global__ __launch_bounds__(1024) void select_kernel_t(
    const float* __restrict__ scores, const float* __restrict__ boxes,
    const int* __restrict__ st_info,
    int* __restrict__ top_idx, float* __restrict__ top_score,
    float* __restrict__ bx1, float* __restrict__ bx2,
    float* __restrict__ by1, float* __restrict__ by2, float* __restrict__ bar) {
  int b = blockIdx.x;
  if (GATED && st_info[b * 2 + 0] >= POST) return;  // fallback not needed
  int tid = threadIdx.x;
  int wv = tid >> 6;
  const float* sc = scores + (size_t)b * NN;

  __shared__ u32 hist16[16][256];   // per-wave privatized histograms
  __shared__ u32 sA[256], sB[256];  // suffix-scan ping-pong
  __shared__ u32 scanbuf[1024];
  __shared__ u64 sortbuf[SELN];
  __shared__ u32 sh_prefix;
  __shared__ int sh_rem;

  const int e0 = tid * 32;
  u32 encs[32];
  {
    const float4* sc4 = (const float4*)(sc + e0);
#pragma unroll
    for (int k = 0; k < 8; ++k) {
      float4 v = sc4[k];
      encs[k * 4 + 0] = enc_f32(v.x);
      encs[k * 4 + 1] = enc_f32(v.y);
      encs[k * 4 + 2] = enc_f32(v.z);
      encs[k * 4 + 3] = enc_f32(v.w);
    }
  }

  u32 prefix = 0, known = 0;
  int remaining = SELN;
  for (int shift = 24; shift >= 0; shift -= 8) {
    for (int k = tid; k < 16 * 256; k += 1024) ((u32*)hist16)[k] = 0;
    __syncthreads();
#pragma unroll
    for (int k = 0; k < 32; ++k) {
      u32 u = encs[k];
      if ((u & known) == prefix) atomicAdd(&hist16[wv][(u >> shift) & 255u], 1u);
    }
    __syncthreads();
    if (tid < 256) {
      u32 t = 0;
#pragma unroll
      for (int w2 = 0; w2 < 16; ++w2) t += hist16[w2][tid];
      sA[tid] = t;
    }
    __syncthreads();
    u32* src = sA; u32* dst = sB;
    for (int off = 1; off < 256; off <<= 1) {
      if (tid < 256) dst[tid] = src[tid] + ((tid + off < 256) ? src[tid + off] : 0u);
      __syncthreads();
      u32* tp = src; src = dst; dst = tp;
    }
    if (tid < 256) {
      u32 sv = src[tid];
      u32 svn = (tid < 255) ? src[tid + 1] : 0u;
      if (sv >= (u32)remaining && svn < (u32)remaining) {
        sh_prefix = prefix | ((u32)tid << shift);
        sh_rem = remaining - (int)svn;
      }
    }
    __syncthreads();
    prefix = sh_prefix;
    remaining = sh_rem;
    known |= (0xFFu << shift);
    __syncthreads();
  }
  const u32 pivot = prefix;

  int gtc = 0, eqc = 0;
#pragma unroll
  for (int k = 0; k < 32; ++k) {
    gtc += (encs[k] > pivot);
    eqc += (encs[k] == pivot);
  }
  scanbuf[tid] = ((u32)gtc << 16) | (u32)eqc;
  __syncthreads();
  for (int off = 1; off < 1024; off <<= 1) {
    u32 v = scanbuf[tid];
    u32 add = (tid >= off) ? scanbuf[tid - off] : 0u;
    __syncthreads();
    scanbuf[tid] = v + add;
    __syncthreads();
  }
  u32 incl = scanbuf[tid];
  u32 totpk = scanbuf[1023];
  const int cnt_gt = (int)(totpk >> 16);
  int gt_base = (int)(incl >> 16) - gtc;
  int eq_base = (int)(incl & 0xFFFFu) - eqc;
  int gs = 0, es = 0;
#pragma unroll
  for (int k = 0; k < 32; ++k) {
    u32 u = encs[k];
    int e = e0 + k;
    u64 key = ((u64)u << 32) | (u32)(~(u32)e);
    if (u > pivot) {
      sortbuf[SW(gt_base + gs)] = key; gs++;
    } else if (u == pivot) {
      int g = eq_base + (es++);
      if (g < remaining) sortbuf[SW(cnt_gt + g)] = key;
    }
  }
  __syncthreads();

  for (int k = 2; k <= SELN; k <<= 1) {
    for (int j = k >> 1; j > 0; j >>= 1) {
      for (int p = tid; p < SELN / 2; p += 1024) {
        int low = p & (j - 1);
        int i = ((p ^ low) << 1) | low;
        int ixj = i + j;
        u64 a = sortbuf[SW(i)], c = sortbuf[SW(ixj)];
        bool desc = ((i & k) == 0);
        if (desc ? (a < c) : (a > c)) { sortbuf[SW(i)] = c; sortbuf[SW(ixj)] = a; }
      }
      __syncthreads();
    }
  }
  {
#pragma clang fp contract(off)
    for (int s = tid; s < SELN; s += 1024) {
      u64 key = sortbuf[SW(s)];
      int e = (int)(~(u32)(key & 0xFFFFFFFFull));
      top_idx[b * PRE + s] = e;
      top_score[b * PRE + s] = sc[e];
      const float* bx = boxes + ((size_t)b * NN + e) * 7;
      float x = bx[0], y = bx[1], dx = bx[3], dy = bx[4];
      float hx = dx * 0.5f, hy = dy * 0.5f;
      bx1[b * PRE + s] = x - hx;
      bx2[b * PRE + s] = x + hx;
      by1[b * PRE + s] = y - hy;
      by2[b * PRE + s] = y + hy;
      bar[b * PRE + s] = dx * dy;
    }
  }
}

// ---------------- kernel 3: suppression bitmask (iou > 0.7, j > i) ----------
__device__ __forceinline__ void mask_tile(
    const float* __restrict__ bx1, const float* __restrict__ bx2,
    const float* __restrict__ by1, const float* __restrict__ by2,
    const float* __restrict__ bar, u64* __restrict__ mask,
    int b, int rb, int cb, int t) {
#pragma clang fp contract(off)
  int i = rb * 64 + t;
  int j0 = cb * 64 + t;
  float cx1 = bx1[b * PRE + j0], cx2 = bx2[b * PRE + j0];
  float cy1 = by1[b * PRE + j0], cy2 = by2[b * PRE + j0];
  float car = bar[b * PRE + j0];
  float ix1 = bx1[b * PRE + i], ix2 = bx2[b * PRE + i];
  float iy1 = by1[b * PRE + i], iy2 = by2[b * PRE + i];
  float ia = bar[b * PRE + i];
  u64 bits = 0ull;
  int jbase = cb * 64;
  for (int jj = 0; jj < 64; ++jj) {
    float jx1 = __shfl(cx1, jj, 64);
    float jx2 = __shfl(cx2, jj, 64);
    float jy1 = __shfl(cy1, jj, 64);
    float jy2 = __shfl(cy2, jj, 64);
    float jar = __shfl(car, jj, 64);
    if (jbase + jj > i) {
      float iw = fminf(ix2, jx2) - fmaxf(ix1, jx1);
      iw = fmaxf(iw, 0.0f);
      float ih = fminf(iy2, jy2) - fmaxf(iy1, jy1);
      ih = fmaxf(ih, 0.0f);
      float inter = iw * ih;
      float uni = ia + jar - inter;
      float iou = inter / fmaxf(uni, 1e-6f);
      if (iou > 0.7f) bits |= (1ull << jj);
    }
  }
  mask[((size_t)b * PRE + i) * NW + cb] = bits;
}

__global__ void mask_prefix_kernel(const float* __restrict__ bx1, const float* __restrict__ bx2,
                                   const float* __restrict__ by1, const float* __restrict__ by2,
                                   const float* __restrict__ bar, u64* __restrict__ mask) {
  int cb = blockIdx.x, rb = blockIdx.y, b = blockIdx.z;
  if (cb < rb) return;
  mask_tile(bx1, bx2, by1, by2, bar, mask, b, rb, cb, threadIdx.x);
}

__global__ __launch_bounds__(256) void mask_full_kernel(
    const float* __restrict__ bx1, const float* __restrict__ bx2,
    const float* __restrict__ by1, const float* __restrict__ by2,
    const float* __restrict__ bar, u64* __restrict__ mask,
    const int* __restrict__ st_info) {
  int b = blockIdx.z;
  if (st_info[b * 2 + 0] >= POST) return;
  int rb = blockIdx.y;
  int cb = blockIdx.x * 4 + (threadIdx.x >> 6);
  if (cb < rb) return;
  mask_tile(bx1, bx2, by1, by2, bar, mask, b, rb, cb, threadIdx.x & 63);
}

// ---------------- kernel 4: chunked greedy NMS, 4 waves per batch -----------
template<bool FULL>
__global__ __launch_bounds__(256) void nms_kernel_t(
    const u64* __restrict__ mask, u64* __restrict__ keep_words,
    int* __restrict__ st_info) {
  int b = blockIdx.x;
  if (FULL && st_info[b * 2 + 0] >= POST) return;  // hot path already done
  int tid = threadIdx.x;
  int lane = tid & 63;
  int wv = tid >> 6;
  __shared__ u64 part[2][4][64];

  const u64* base = mask + (size_t)b * PRE * NW;
  u64 rem = 0ull, keepw = 0ull;
  int kept = 0;
  const int c1 = FULL ? NW : PREF_CH;

  int c = 0;
  while (c < c1) {
    u64 remc = __shfl(rem, c, 64);
    const u64* rowp = base + ((size_t)(c * 64 + wv * 16)) * NW + lane;
    u64 m[16];
#pragma unroll
    for (int k = 0; k < 16; ++k) m[k] = rowp[(size_t)k * NW];
    u64 dg = base[((size_t)(c * 64 + lane)) * NW + c];
    u64 nz = __ballot(dg != 0ull);
    while (nz) {
      int i2 = __builtin_ctzll(nz);
      nz &= nz - 1ull;
      u64 di = __shfl(dg, i2, 64);
      if (!((remc >> i2) & 1ull)) remc |= di;
    }
    u64 K = ~remc;
    if (lane == c) keepw = K;
    kept += __popcll(K);

    u32 kb = (u32)((K >> (wv * 16)) & 0xFFFFull);
    u64 acc = 0ull;
#pragma unroll
    for (int k = 0; k < 16; ++k)
      if ((kb >> k) & 1u) acc |= m[k];
    part[c & 1][wv][lane] = acc;
    __syncthreads();
    rem |= part[c & 1][0][lane] | part[c & 1][1][lane] |
           part[c & 1][2][lane] | part[c & 1][3][lane];
    ++c;
    if (kept >= POST) break;  // uniform; later output ranks all >= POST
  }

  if (wv == 0) {
    keep_words[b * 64 + lane] = keepw;  // unprocessed chunks -> 0
    if (!FULL && lane == 0) st_info[b * 2 + 0] = kept;
  }
}

// ---------------- kernel 5: emit first POST kept entries --------------------
__global__ __launch_bounds__(1024) void output_kernel(
    const u64* __restrict__ keep_words, const int* __restrict__ top_idx,
    const float* __restrict__ top_score, const int* __restrict__ labels,
    const float* __restrict__ boxes, float* __restrict__ out) {
  int b = blockIdx.x, tid = threadIdx.x;
  __shared__ u32 scanbuf[1024];
  __shared__ int sh_total;

  u64 w = keep_words[b * 64 + (tid >> 4)];
  u32 my4 = (u32)((w >> ((tid & 15) * 4)) & 0xFull);  // 4 consecutive i per thread
  int cnt = __popc(my4);
  scanbuf[tid] = (u32)cnt;
  __syncthreads();
  for (int off = 1; off < 1024; off <<= 1) {
    u32 v = scanbuf[tid];
    u32 add = (tid >= off) ? scanbuf[tid - off] : 0u;
    __syncthreads();
    scanbuf[tid] = v + add;
    __syncthreads();
  }
  int base = (int)scanbuf[tid] - cnt;
  if (tid == 1023) sh_total = (int)scanbuf[1023];
  __syncthreads();
  int total = sh_total;

  float* rois = out;                 // BB*POST*7
  float* rsc = out + BB * POST * 7;  // BB*POST
  float* rlb = rsc + BB * POST;      // BB*POST (labels as f32)

  int r = 0;
  for (int k = 0; k < 4; ++k) {
    if ((my4 >> k) & 1u) {
      int rank = base + (r++);
      if (rank < POST) {
        int i = tid * 4 + k;
        int idx = top_idx[b * PRE + i];
        const float* bx = boxes + ((size_t)b * NN + idx) * 7;
        float* ro = rois + ((size_t)b * POST + rank) * 7;
        for (int c = 0; c < 7; ++c) ro[c] = bx[c];
        rsc[b * POST + rank] = top_score[b * PRE + i];
        rlb[b * POST + rank] = (float)(labels[b * NN + idx] + 1);
      }
    }
  }
  // invalid slots: rois = 0, score = 0, label = 0 + 1
  for (int s = tid; s < POST; s += 1024) {
    if (s >= total) {
      float* ro = rois + ((size_t)b * POST + s) * 7;
      for (int c = 0; c < 7; ++c) ro[c] = 0.0f;
      rsc[b * POST + s] = 0.0f;
      rlb[b * POST + s] = 1.0f;
    }
  }
}

// ---------------------------------------------------------------------------
extern "C" void kernel_launch(void* const* d_in, const int* in_sizes, int n_in,
                              void* d_out, int out_size, void* d_ws, size_t ws_size,
                              hipStream_t stream) {
  const float* boxes = (const float*)d_in[0];  // (B, N, 7)
  const float* cls = (const float*)d_in[1];    // (B, N, 3)
  float* out = (float*)d_out;                  // rois | scores | labels, flat f32

  char* w = (char*)d_ws;
  float* scores = (float*)w;    w += (size_t)BB * NN * 4;
  int* labels = (int*)w;        w += (size_t)BB * NN * 4;
  int* top_idx = (int*)w;       w += (size_t)BB * PRE * 4;
  float* top_score = (float*)w; w += (size_t)BB * PRE * 4;
  float* bx1 = (float*)w;       w += (size_t)BB * PRE * 4;
  float* bx2 = (float*)w;       w += (size_t)BB * PRE * 4;
  float* by1 = (float*)w;       w += (size_t)BB * PRE * 4;
  float* by2 = (float*)w;       w += (size_t)BB * PRE * 4;
  float* bar = (float*)w;       w += (size_t)BB * PRE * 4;
  u64* mask = (u64*)w;          w += (size_t)BB * PRE * NW * 8;
  u64* keepw = (u64*)w;         w += (size_t)BB * 64 * 8;
  int* st_info = (int*)w;       w += (size_t)BB * 2 * 4;

  // hot path: top-1024 prefix only
  score_kernel<<<(BB * NN + 255) / 256, 256, 0, stream>>>(cls, scores, labels);
  select_fast_kernel<<<BB, 1024, 0, stream>>>(
      scores, boxes, top_idx, top_score, bx1, bx2, by1, by2, bar);
  mask_prefix_kernel<<<dim3(PREF_CH, PREF_CH, BB), 64, 0, stream>>>(
      bx1, bx2, by1, by2, bar, mask);
  nms_kernel_t<false><<<BB, 256, 0, stream>>>(mask, keepw, st_info);
  // fallback chain (exits immediately when prefix found >= POST keepers)
  select_kernel_t<PRE, true><<<BB, 1024, 0, stream>>>(
      scores, boxes, st_info, top_idx, top_score, bx1, bx2, by1, by2, bar);
  mask_full_kernel<<<dim3(NW / 4, NW, BB), 256, 0, stream>>>(
      bx1, bx2, by1, by2, bar, mask, st_info);
  nms_kernel_t<true><<<BB, 256, 0, stream>>>(mask, keepw, st_info);
  // output
  output_kernel<<<BB, 1024, 0, stream>>>(keepw, top_idx, top_score, labels, boxes, out);
}